// Round 1
// baseline (1006.860 us; speedup 1.0000x reference)
//
#include <hip/hip_runtime.h>

typedef float  f4  __attribute__((ext_vector_type(4)));
typedef __bf16 bf8 __attribute__((ext_vector_type(8)));
typedef short  s8  __attribute__((ext_vector_type(8)));

#define BIGF 1e8f
#define CFENCE() __asm__ volatile("" ::: "memory")

__device__ inline unsigned short f2bf_bits(float f) {
    unsigned u = __float_as_uint(f);
    u += 0x7fffu + ((u >> 16) & 1u);   // RNE to bf16
    return (unsigned short)(u >> 16);
}

// ---------------- W transpose + bf16 convert: Wt[n][k] = bf16(W[k][n]) ----------------
__global__ __launch_bounds__(256) void wtrans_kernel(const float* __restrict__ W,
                                                     unsigned short* __restrict__ Wt) {
    int idx = blockIdx.x * 256 + threadIdx.x;
    if (idx < 768 * 128) {
        int k = idx >> 7, n = idx & 127;
        Wt[n * 768 + k] = f2bf_bits(W[idx]);
    }
}

// ---------------- projection: Out = bf16(l2norm(In @ W + b)), 128-row tiles ----------------
__global__ __launch_bounds__(256) void proj_kernel(const float* __restrict__ In,
                                                   const unsigned short* __restrict__ Wt,
                                                   const float* __restrict__ bias,
                                                   unsigned short* __restrict__ Out) {
    int tid = threadIdx.x;
    int wave = tid >> 6, lane = tid & 63;
    int quad = lane >> 4, rq = lane & 15;
    int rh = (wave >> 1) * 64, ch = (wave & 1) * 64;
    long rowBase = (long)blockIdx.x * 128 + rh;

    f4 acc[4][4];
#pragma unroll
    for (int a = 0; a < 4; ++a)
#pragma unroll
        for (int b = 0; b < 4; ++b) acc[a][b] = 0.0f;

    for (int kc = 0; kc < 24; ++kc) {
        int k0 = kc * 32 + quad * 8;
        bf8 af[4], bfr[4];
#pragma unroll
        for (int t = 0; t < 4; ++t) {
            const float* ap = In + (rowBase + t * 16 + rq) * 768 + k0;
            f4 u0 = *(const f4*)ap;
            f4 u1 = *(const f4*)(ap + 4);
            s8 tmp;
            tmp[0] = (short)f2bf_bits(u0[0]); tmp[1] = (short)f2bf_bits(u0[1]);
            tmp[2] = (short)f2bf_bits(u0[2]); tmp[3] = (short)f2bf_bits(u0[3]);
            tmp[4] = (short)f2bf_bits(u1[0]); tmp[5] = (short)f2bf_bits(u1[1]);
            tmp[6] = (short)f2bf_bits(u1[2]); tmp[7] = (short)f2bf_bits(u1[3]);
            af[t] = __builtin_bit_cast(bf8, tmp);
            bfr[t] = *(const bf8*)(const void*)(Wt + (ch + t * 16 + rq) * 768 + k0);
        }
#pragma unroll
        for (int ti = 0; ti < 4; ++ti)
#pragma unroll
            for (int tj = 0; tj < 4; ++tj)
                acc[ti][tj] = __builtin_amdgcn_mfma_f32_16x16x32_bf16(af[ti], bfr[tj], acc[ti][tj], 0, 0, 0);
    }

    __shared__ float ssq[128];
    if (tid < 128) ssq[tid] = 0.f;
    __syncthreads();

    float b4[4];
#pragma unroll
    for (int tj = 0; tj < 4; ++tj) b4[tj] = bias[ch + tj * 16 + rq];

#pragma unroll
    for (int ti = 0; ti < 4; ++ti)
#pragma unroll
        for (int r = 0; r < 4; ++r) {
            float p = 0.f;
#pragma unroll
            for (int tj = 0; tj < 4; ++tj) {
                float z = acc[ti][tj][r] + b4[tj];
                p += z * z;
            }
            atomicAdd(&ssq[rh + ti * 16 + quad * 4 + r], p);
        }
    __syncthreads();

#pragma unroll
    for (int ti = 0; ti < 4; ++ti)
#pragma unroll
        for (int r = 0; r < 4; ++r) {
            int rowL = rh + ti * 16 + quad * 4 + r;
            float rn = rsqrtf(ssq[rowL]);
#pragma unroll
            for (int tj = 0; tj < 4; ++tj) {
                float z = (acc[ti][tj][r] + b4[tj]) * rn;
                Out[((long)blockIdx.x * 128 + rowL) * 128 + ch + tj * 16 + rq] = f2bf_bits(z);
            }
        }
}

// ------------- gram: S[b][i][i+j] = fp16(2 - 2 * x_i . y_j) (per-row diagonal stream) -------------
__global__ __launch_bounds__(256) void gram_kernel(const unsigned short* __restrict__ X,
                                                   const unsigned short* __restrict__ Y,
                                                   _Float16* __restrict__ S,
                                                   int N, int M, int Nd8) {
    int b = blockIdx.z;
    long i0 = (long)blockIdx.x * 128, j0 = (long)blockIdx.y * 128;
    const unsigned short* Xb = X + (long)b * N * 128;
    const unsigned short* Yb = Y + (long)b * M * 128;
    _Float16* Sb = S + (long)b * N * Nd8;
    int tid = threadIdx.x, wave = tid >> 6, lane = tid & 63;
    int quad = lane >> 4, rq = lane & 15;
    int rh = (wave >> 1) * 64, ch = (wave & 1) * 64;

    f4 acc[4][4];
#pragma unroll
    for (int a = 0; a < 4; ++a)
#pragma unroll
        for (int c = 0; c < 4; ++c) acc[a][c] = 0.0f;

#pragma unroll
    for (int kc = 0; kc < 4; ++kc) {
        int k0 = kc * 32 + quad * 8;
        bf8 af[4], bfr[4];
#pragma unroll
        for (int t = 0; t < 4; ++t) {
            af[t]  = *(const bf8*)(const void*)(Xb + (i0 + rh + t * 16 + rq) * 128 + k0);
            bfr[t] = *(const bf8*)(const void*)(Yb + (j0 + ch + t * 16 + rq) * 128 + k0);
        }
#pragma unroll
        for (int ti = 0; ti < 4; ++ti)
#pragma unroll
            for (int tj = 0; tj < 4; ++tj)
                acc[ti][tj] = __builtin_amdgcn_mfma_f32_16x16x32_bf16(af[ti], bfr[tj], acc[ti][tj], 0, 0, 0);
    }

#pragma unroll
    for (int ti = 0; ti < 4; ++ti)
#pragma unroll
        for (int r = 0; r < 4; ++r) {
            long gi = i0 + rh + ti * 16 + quad * 4 + r;
#pragma unroll
            for (int tj = 0; tj < 4; ++tj) {
                long gj = j0 + ch + tj * 16 + rq;
                Sb[gi * Nd8 + gi + gj] = (_Float16)(2.0f - 2.0f * acc[ti][tj][r]);
            }
        }
}

// ---------------- soft-DTW wavefront DP, one workgroup per (batch, matrix) ----------------
__global__ __launch_bounds__(1024) void dp_kernel(const _Float16* __restrict__ Sxy,
                                                  const _Float16* __restrict__ Sxx,
                                                  const _Float16* __restrict__ Syy,
                                                  float* __restrict__ out) {
    int type = blockIdx.y, b = blockIdx.x;
    const _Float16* Db; int N, Nd, Nd8; float w;
    if (type == 0)      { Db = Sxy; N = 1024; Nd = 1791; Nd8 = 1792; w =  1.0f; }
    else if (type == 1) { Db = Sxx; N = 1024; Nd = 2047; Nd8 = 2048; w = -0.5f; }
    else                { Db = Syy; N =  768; Nd = 1535; Nd8 = 1536; w = -0.5f; }
    float scale = w * (1.0f / 28672.0f);   // / (B=16 * total_seq_len=1792)

    __shared__ float buf[3][1025];
    float* buf0 = buf[0]; float* buf1 = buf[1]; float* buf2 = buf[2];
    int i = threadIdx.x;

    for (int idx = i; idx <= N; idx += 1024) {
        buf0[idx] = (idx == 0) ? 0.f : BIGF;   // vm2 at d=0 (R[-1,-1]=0 start cell)
        buf1[idx] = BIGF;                      // vm1 at d=0
    }
    bool act = (i < N);
    const uint4* rp = nullptr; uint4 cur = {}, nxt = {};
    if (act) {
        rp = (const uint4*)(const void*)(Db + (long)b * N * Nd8 + (long)i * Nd8);
        cur = rp[0];   // chunk for d = 0..7
        nxt = rp[1];   // chunk for d = 8..15
    }
    __syncthreads();

    int nG = (Nd + 23) / 24;
    int d0 = 0;
    for (int g = 0; g < nG; ++g, d0 += 24) {
#pragma unroll
        for (int u = 0; u < 24; ++u) {
            int d = d0 + u;
            if (d < Nd) {
                if (act) {
                    const int ph = u & 7;            // == d & 7 (24*g is mult of 8)
                    if (ph == 0 && d > 0) {          // uniform refill, 8-step-old load -> hidden
                        cur = nxt;
                        if ((d + 8) < Nd8) nxt = rp[(d >> 3) + 1];
                    }
                    unsigned wrd = (ph < 2) ? cur.x : (ph < 4) ? cur.y : (ph < 6) ? cur.z : cur.w;
                    unsigned hb = (ph & 1) ? (wrd >> 16) : (wrd & 0xffffu);
                    float dv = (float)__builtin_bit_cast(_Float16, (unsigned short)hb);

                    float* vm2 = (u % 3 == 0) ? buf0 : (u % 3 == 1) ? buf1 : buf2;
                    float* vm1 = (u % 3 == 0) ? buf1 : (u % 3 == 1) ? buf2 : buf0;
                    float* vnw = (u % 3 == 0) ? buf2 : (u % 3 == 1) ? buf0 : buf1;

                    float a  = vm2[i];       // R[i-1][j-1]
                    float bb = vm1[i];       // R[i-1][j]
                    float cc = vm1[i + 1];   // R[i][j-1]
                    float m = fminf(fminf(a, bb), cc);
                    float s = __expf((m - a) * 10.f) + __expf((m - bb) * 10.f) + __expf((m - cc) * 10.f);
                    float val = dv + m - 0.1f * __logf(s);
                    val = (val < BIGF) ? val : BIGF;    // NaN/overflow guard (poisoned border cells)
                    vnw[i + 1] = val;
                    if (i == 0) vnw[0] = BIGF;
                }
                // barrier WITHOUT vmcnt drain: keep D prefetch in flight across diagonals
                CFENCE();
                __builtin_amdgcn_s_waitcnt(0xC07F);   // lgkmcnt(0) only (vmcnt=63, expcnt=7)
                __builtin_amdgcn_s_barrier();
                CFENCE();
            }
        }
    }
    if (i == 0) {
        int r = (Nd + 1) % 3;    // buffer holding the last diagonal
        float* vb = (r == 0) ? buf0 : (r == 1) ? buf1 : buf2;
        atomicAdd(out, scale * vb[N]);   // R[N-1][M-1]
    }
}

// ---------------- host launcher ----------------
extern "C" void kernel_launch(void* const* d_in, const int* in_sizes, int n_in,
                              void* d_out, int out_size, void* d_ws, size_t ws_size,
                              hipStream_t stream) {
    (void)in_sizes; (void)n_in; (void)out_size; (void)ws_size;
    const float* feats = (const float*)d_in[0];   // [16,1024,768]
    const float* targ  = (const float*)d_in[1];   // [16,768,768]
    const float* W     = (const float*)d_in[2];   // [768,128]
    const float* bias  = (const float*)d_in[3];   // [128]

    char* ws = (char*)d_ws;
    unsigned short* xbf = (unsigned short*)(ws + 0);            // 16384x128 bf16 = 4 MB
    unsigned short* ybf = (unsigned short*)(ws + 4194304);      // 12288x128 bf16 = 3 MB
    unsigned short* Wt  = (unsigned short*)(ws + 7340032);      // 128x768 bf16
    _Float16* SxyS = (_Float16*)(ws + 7536640);                 // 16x1024x1792 fp16
    _Float16* SxxS = (_Float16*)(ws + 66256896);                // 16x1024x2048 fp16
    _Float16* SyyS = (_Float16*)(ws + 133365760);               // 16x768x1536  fp16
    // total ws use: 171,114,496 bytes

    hipMemsetAsync(d_out, 0, sizeof(float), stream);

    wtrans_kernel<<<384, 256, 0, stream>>>(W, Wt);
    proj_kernel<<<128, 256, 0, stream>>>(feats, Wt, bias, xbf);
    proj_kernel<<<96, 256, 0, stream>>>(targ, Wt, bias, ybf);

    gram_kernel<<<dim3(8, 6, 16), 256, 0, stream>>>(xbf, ybf, SxyS, 1024,  768, 1792);
    gram_kernel<<<dim3(8, 8, 16), 256, 0, stream>>>(xbf, xbf, SxxS, 1024, 1024, 2048);
    gram_kernel<<<dim3(6, 6, 16), 256, 0, stream>>>(ybf, ybf, SyyS,  768,  768, 1536);

    dp_kernel<<<dim3(16, 3), 1024, 0, stream>>>(SxyS, SxxS, SyyS, (float*)d_out);
}

// Round 4
// 714.714 us; speedup vs baseline: 1.4088x; 1.4088x over previous
//
#include <hip/hip_runtime.h>

typedef float  f4  __attribute__((ext_vector_type(4)));
typedef __bf16 bf8 __attribute__((ext_vector_type(8)));
typedef short  s8  __attribute__((ext_vector_type(8)));
typedef int    i2  __attribute__((ext_vector_type(2)));

__device__ inline unsigned short f2bf_bits(float f) {
    unsigned u = __float_as_uint(f);
    u += 0x7fffu + ((u >> 16) & 1u);   // RNE to bf16
    return (unsigned short)(u >> 16);
}

// ---------------- W transpose + bf16 convert: Wt[n][k] = bf16(W[k][n]) ----------------
__global__ __launch_bounds__(256) void wtrans_kernel(const float* __restrict__ W,
                                                     unsigned short* __restrict__ Wt) {
    int idx = blockIdx.x * 256 + threadIdx.x;
    if (idx < 768 * 128) {
        int k = idx >> 7, n = idx & 127;
        Wt[n * 768 + k] = f2bf_bits(W[idx]);
    }
}

// ---------------- projection: Out = bf16(l2norm(In @ W + b)), 128-row tiles ----------------
__global__ __launch_bounds__(256) void proj_kernel(const float* __restrict__ In,
                                                   const unsigned short* __restrict__ Wt,
                                                   const float* __restrict__ bias,
                                                   unsigned short* __restrict__ Out) {
    int tid = threadIdx.x;
    int wave = tid >> 6, lane = tid & 63;
    int quad = lane >> 4, rq = lane & 15;
    int rh = (wave >> 1) * 64, ch = (wave & 1) * 64;
    long rowBase = (long)blockIdx.x * 128 + rh;

    f4 acc[4][4];
#pragma unroll
    for (int a = 0; a < 4; ++a)
#pragma unroll
        for (int b = 0; b < 4; ++b) acc[a][b] = 0.0f;

    for (int kc = 0; kc < 24; ++kc) {
        int k0 = kc * 32 + quad * 8;
        bf8 af[4], bfr[4];
#pragma unroll
        for (int t = 0; t < 4; ++t) {
            const float* ap = In + (rowBase + t * 16 + rq) * 768 + k0;
            f4 u0 = *(const f4*)ap;
            f4 u1 = *(const f4*)(ap + 4);
            s8 tmp;
            tmp[0] = (short)f2bf_bits(u0[0]); tmp[1] = (short)f2bf_bits(u0[1]);
            tmp[2] = (short)f2bf_bits(u0[2]); tmp[3] = (short)f2bf_bits(u0[3]);
            tmp[4] = (short)f2bf_bits(u1[0]); tmp[5] = (short)f2bf_bits(u1[1]);
            tmp[6] = (short)f2bf_bits(u1[2]); tmp[7] = (short)f2bf_bits(u1[3]);
            af[t] = __builtin_bit_cast(bf8, tmp);
            bfr[t] = *(const bf8*)(const void*)(Wt + (ch + t * 16 + rq) * 768 + k0);
        }
#pragma unroll
        for (int ti = 0; ti < 4; ++ti)
#pragma unroll
            for (int tj = 0; tj < 4; ++tj)
                acc[ti][tj] = __builtin_amdgcn_mfma_f32_16x16x32_bf16(af[ti], bfr[tj], acc[ti][tj], 0, 0, 0);
    }

    __shared__ float ssq[128];
    if (tid < 128) ssq[tid] = 0.f;
    __syncthreads();

    float b4[4];
#pragma unroll
    for (int tj = 0; tj < 4; ++tj) b4[tj] = bias[ch + tj * 16 + rq];

#pragma unroll
    for (int ti = 0; ti < 4; ++ti)
#pragma unroll
        for (int r = 0; r < 4; ++r) {
            float p = 0.f;
#pragma unroll
            for (int tj = 0; tj < 4; ++tj) {
                float z = acc[ti][tj][r] + b4[tj];
                p += z * z;
            }
            atomicAdd(&ssq[rh + ti * 16 + quad * 4 + r], p);
        }
    __syncthreads();

#pragma unroll
    for (int ti = 0; ti < 4; ++ti)
#pragma unroll
        for (int r = 0; r < 4; ++r) {
            int rowL = rh + ti * 16 + quad * 4 + r;
            float rn = rsqrtf(ssq[rowL]);
#pragma unroll
            for (int tj = 0; tj < 4; ++tj) {
                float z = (acc[ti][tj][r] + b4[tj]) * rn;
                Out[((long)blockIdx.x * 128 + rowL) * 128 + ch + tj * 16 + rq] = f2bf_bits(z);
            }
        }
}

// ------- gram: E[b][i][d=i+j] = bf16(exp((2*dot-2)*10)) = exp(-D/gamma), diagonal stream -------
__global__ __launch_bounds__(256) void gram_kernel(const unsigned short* __restrict__ X,
                                                   const unsigned short* __restrict__ Y,
                                                   unsigned short* __restrict__ S,
                                                   int N, int M, int Nd8) {
    int b = blockIdx.z;
    long i0 = (long)blockIdx.x * 128, j0 = (long)blockIdx.y * 128;
    const unsigned short* Xb = X + (long)b * N * 128;
    const unsigned short* Yb = Y + (long)b * M * 128;
    unsigned short* Sb = S + (long)b * N * Nd8;
    int tid = threadIdx.x, wave = tid >> 6, lane = tid & 63;
    int quad = lane >> 4, rq = lane & 15;
    int rh = (wave >> 1) * 64, ch = (wave & 1) * 64;

    f4 acc[4][4];
#pragma unroll
    for (int a = 0; a < 4; ++a)
#pragma unroll
        for (int c = 0; c < 4; ++c) acc[a][c] = 0.0f;

#pragma unroll
    for (int kc = 0; kc < 4; ++kc) {
        int k0 = kc * 32 + quad * 8;
        bf8 af[4], bfr[4];
#pragma unroll
        for (int t = 0; t < 4; ++t) {
            af[t]  = *(const bf8*)(const void*)(Xb + (i0 + rh + t * 16 + rq) * 128 + k0);
            bfr[t] = *(const bf8*)(const void*)(Yb + (j0 + ch + t * 16 + rq) * 128 + k0);
        }
#pragma unroll
        for (int ti = 0; ti < 4; ++ti)
#pragma unroll
            for (int tj = 0; tj < 4; ++tj)
                acc[ti][tj] = __builtin_amdgcn_mfma_f32_16x16x32_bf16(af[ti], bfr[tj], acc[ti][tj], 0, 0, 0);
    }

#pragma unroll
    for (int ti = 0; ti < 4; ++ti)
#pragma unroll
        for (int r = 0; r < 4; ++r) {
            long gi = i0 + rh + ti * 16 + quad * 4 + r;
#pragma unroll
            for (int tj = 0; tj < 4; ++tj) {
                long gj = j0 + ch + tj * 16 + rq;
                float Ev = __expf(20.0f * acc[ti][tj][r] - 20.0f);
                Sb[gi * Nd8 + gi + gj] = f2bf_bits(Ev);
            }
        }
}

// ---------------- soft-DTW alpha-space DP (fp64), ONE WAVE per (batch, matrix) ----------------
__device__ inline double wshr1_d(double x) {  // lane l <- lane l-1, lane 0 <- 0
    i2 v = __builtin_bit_cast(i2, x);
    v.x = __builtin_amdgcn_update_dpp(0, v.x, 0x138, 0xf, 0xf, false);
    v.y = __builtin_amdgcn_update_dpp(0, v.y, 0x138, 0xf, 0xf, false);
    return __builtin_bit_cast(double, v);
}
#define DPPMAXI(x, ctrl) max((x), __builtin_amdgcn_update_dpp(0, (x), (ctrl), 0xf, 0xf, false))
__device__ inline int redmax64_i(int x) {   // full max in lane 63 (patterns >= 0)
    x = DPPMAXI(x, 0x111);  // row_shr:1
    x = DPPMAXI(x, 0x112);  // row_shr:2
    x = DPPMAXI(x, 0x114);  // row_shr:4
    x = DPPMAXI(x, 0x118);  // row_shr:8
    x = DPPMAXI(x, 0x142);  // row_bcast15
    x = DPPMAXI(x, 0x143);  // row_bcast31
    return x;
}
__device__ inline int hiw(double x) { return __builtin_bit_cast(i2, x).y; }

template<int K, int N, int M, int ND8, int NG>
__device__ void dp_impl(const unsigned short* __restrict__ E, float wscale, float* __restrict__ out) {
    const int lane = threadIdx.x;
    const char* Eb = (const char*)(E + (long)blockIdx.x * N * ND8);
    unsigned off[K];
    uint4 eA[K], eB[K];
    double vA[K], vB[K];
#pragma unroll
    for (int r = 0; r < K; ++r) {
        off[r] = (unsigned)((K * lane + r) * ND8 * 2);
        vA[r] = 0.0; vB[r] = 0.0;
        eA[r] = *(const uint4*)(const void*)(Eb + off[r]);   // chunk 0: d = 0..7
    }
    double seed = (lane == 0) ? 1.0 : 0.0;   // alpha[-1][-1] = 1 seed, consumed at d==0
    int ls = 0;                              // accumulated log2 scale (wave-uniform)

#define EGETV(EQ, PH) __uint_as_float(((PH) & 1) ? ((&(EQ).x)[(PH) >> 1] & 0xffff0000u) \
                                                 : ((&(EQ).x)[(PH) >> 1] << 16))
    // one anti-diagonal: writes W (held A[d-2], becomes A[d]), reads P1 (= A[d-1])
#define DSTEP(W, P1, EB_, PH) do { \
        double b1 = wshr1_d(P1[K - 1]); \
        double b2 = wshr1_d(W[K - 1]) + seed; seed = 0.0; \
        double p2 = b2, p1m = b1; \
        _Pragma("unroll") \
        for (int r = 0; r < K; ++r) { \
            double told = W[r]; double c1 = P1[r]; \
            double Ed = (double)EGETV(EB_[r], PH); \
            W[r] = Ed * (p2 + p1m + c1); \
            p2 = told; p1m = c1; \
        } } while (0)

    // pow2 rescale of BOTH live diagonals: joint max -> ~2^980. fp64 depth below the
    // anchor is >1900 bits (~130 cost units) even after 8 worst-case e^-40 steps, so
    // nothing reachable is ever flushed. Max via int-max on the hi words (monotone for +).
#define DRESC(W, P1) do { \
        int hm = hiw(W[0]) > hiw(P1[0]) ? hiw(W[0]) : hiw(P1[0]); \
        _Pragma("unroll") \
        for (int r = 1; r < K; ++r) { \
            int h1 = hiw(W[r]), h2 = hiw(P1[r]); \
            if (h1 > hm) hm = h1; if (h2 > hm) hm = h2; } \
        hm = redmax64_i(hm); \
        int hb = __builtin_amdgcn_readlane(hm, 63); \
        if (hb > 0) { \
            int eraw = (hb >> 20) & 0x7ff; \
            int sh = 2003 - eraw;                      /* target exponent 2^980 */ \
            sh = (sh > 1020) ? 1020 : ((sh < -1020) ? -1020 : sh); \
            i2 fb; fb.x = 0; fb.y = (1023 + sh) << 20; \
            double f = __builtin_bit_cast(double, fb); \
            ls += sh; \
            _Pragma("unroll") \
            for (int r = 0; r < K; ++r) { W[r] *= f; P1[r] *= f; } \
        } } while (0)

    for (int g = 0; g < NG; ++g) {
#pragma unroll
        for (int r = 0; r < K; ++r)   // prefetch chunk 2g+1 (used at u=8..15), 8 steps ahead
            eB[r] = *(const uint4*)(const void*)(Eb + (off[r] + 16));
        DSTEP(vA, vB, eA, 0); DSTEP(vB, vA, eA, 1);
        DSTEP(vA, vB, eA, 2); DSTEP(vB, vA, eA, 3);
        DSTEP(vA, vB, eA, 4); DSTEP(vB, vA, eA, 5);
        DSTEP(vA, vB, eA, 6); DSTEP(vB, vA, eA, 7);
        DRESC(vB, vA);
        if (g + 1 < NG) {
#pragma unroll
            for (int r = 0; r < K; ++r)   // prefetch chunk 2g+2 (next group's u=0..7)
                eA[r] = *(const uint4*)(const void*)(Eb + (off[r] + 32));
        }
        DSTEP(vA, vB, eB, 0); DSTEP(vB, vA, eB, 1);
        DSTEP(vA, vB, eB, 2); DSTEP(vB, vA, eB, 3);
        DSTEP(vA, vB, eB, 4); DSTEP(vB, vA, eB, 5);
        DSTEP(vA, vB, eB, 6); DSTEP(vB, vA, eB, 7);
        DRESC(vB, vA);
#pragma unroll
        for (int r = 0; r < K; ++r) off[r] += 32;
    }
    if (lane == 63) {
        // A[N-1][M-1] at d = N+M-2 (even -> vA), row N-1 = lane 63, r = K-1
        double v = vA[K - 1];
        i2 vb = __builtin_bit_cast(i2, v);
        int eraw = (vb.y >> 20) & 0x7ff;
        int ex = eraw - 1022;                       // v = m * 2^ex, m in [0.5,1)
        i2 mb; mb.x = vb.x; mb.y = (vb.y & 0x000FFFFF) | (1022 << 20);
        float mf = (float)__builtin_bit_cast(double, mb);
        if (!(mf > 0.f)) mf = 0.5f;                 // guard (cannot happen if DP sane)
        double R = -0.1 * ((double)logf(mf) + (double)(ex - ls) * 0.6931471805599453);
        atomicAdd(out, wscale * (float)R);
    }
#undef DSTEP
#undef DRESC
#undef EGETV
}

__global__ __launch_bounds__(64) void dp_kernel(const unsigned short* __restrict__ Sxy,
                                                const unsigned short* __restrict__ Sxx,
                                                const unsigned short* __restrict__ Syy,
                                                float* __restrict__ out) {
    if (blockIdx.y == 0)      dp_impl<16, 1024,  768, 1792, 112>(Sxy,  1.0f / 28672.0f, out);
    else if (blockIdx.y == 1) dp_impl<16, 1024, 1024, 2048, 128>(Sxx, -0.5f / 28672.0f, out);
    else                      dp_impl<12,  768,  768, 1536,  96>(Syy, -0.5f / 28672.0f, out);
}

// ---------------- host launcher ----------------
extern "C" void kernel_launch(void* const* d_in, const int* in_sizes, int n_in,
                              void* d_out, int out_size, void* d_ws, size_t ws_size,
                              hipStream_t stream) {
    (void)in_sizes; (void)n_in; (void)out_size; (void)ws_size;
    const float* feats = (const float*)d_in[0];   // [16,1024,768]
    const float* targ  = (const float*)d_in[1];   // [16,768,768]
    const float* W     = (const float*)d_in[2];   // [768,128]
    const float* bias  = (const float*)d_in[3];   // [128]

    char* ws = (char*)d_ws;
    unsigned short* xbf = (unsigned short*)(ws + 0);            // 16384x128 bf16 = 4 MB
    unsigned short* ybf = (unsigned short*)(ws + 4194304);      // 12288x128 bf16 = 3 MB
    unsigned short* Wt  = (unsigned short*)(ws + 7340032);      // 128x768 bf16
    unsigned short* SxyE = (unsigned short*)(ws + 7536640);     // 16x1024x1792 bf16 E
    unsigned short* SxxE = (unsigned short*)(ws + 66256896);    // 16x1024x2048 bf16 E
    unsigned short* SyyE = (unsigned short*)(ws + 133365760);   // 16x768x1536  bf16 E
    // total ws use: 171,114,496 bytes (same envelope as the passing R0 kernel)

    hipMemsetAsync(d_out, 0, sizeof(float), stream);
    // zero all E streams so pad cells (invalid j) are E=0 -> alpha=0 automatically
    hipMemsetAsync(ws + 7536640, 0, 163577856, stream);

    wtrans_kernel<<<384, 256, 0, stream>>>(W, Wt);
    proj_kernel<<<128, 256, 0, stream>>>(feats, Wt, bias, xbf);
    proj_kernel<<<96, 256, 0, stream>>>(targ, Wt, bias, ybf);

    gram_kernel<<<dim3(8, 6, 16), 256, 0, stream>>>(xbf, ybf, SxyE, 1024,  768, 1792);
    gram_kernel<<<dim3(8, 8, 16), 256, 0, stream>>>(xbf, xbf, SxxE, 1024, 1024, 2048);
    gram_kernel<<<dim3(6, 6, 16), 256, 0, stream>>>(ybf, ybf, SyyE,  768,  768, 1536);

    dp_kernel<<<dim3(16, 3), 64, 0, stream>>>(SxyE, SxxE, SyyE, (float*)d_out);
}